// Round 9
// baseline (816.070 us; speedup 1.0000x reference)
//
#include <hip/hip_runtime.h>
#include <stdint.h>

#define NB 32      // B
#define NT 256     // T
#define NS 32      // S
#define NH 512     // H
#define NV 128     // V
#define BT 8192    // B*T

typedef __attribute__((ext_vector_type(8))) __bf16 bf16x8;
typedef __attribute__((ext_vector_type(4))) float f32x4;
typedef __attribute__((ext_vector_type(2))) _Float16 half2v;
typedef unsigned long long u64;

typedef __attribute__((address_space(1))) const unsigned int GASU;
typedef __attribute__((address_space(3))) unsigned int LASU;
#define ASYNC16(g, l) __builtin_amdgcn_global_load_lds((GASU*)(g), (LASU*)(l), 16, 0, 0)

__device__ __forceinline__ half2v pkrtz(float a, float b){
  return __builtin_bit_cast(half2v, __builtin_amdgcn_cvt_pkrtz(a, b));
}
__device__ __forceinline__ unsigned short f2bf(float f){
  unsigned int u = __builtin_bit_cast(unsigned int, f);
  u += 0x7fffu + ((u >> 16) & 1u);
  return (unsigned short)(u >> 16);
}
__device__ __forceinline__ float bf2f(unsigned short h){
  return __builtin_bit_cast(float, ((unsigned int)h) << 16);
}
__device__ __forceinline__ float fexp(float x){ return __builtin_amdgcn_exp2f(x * 1.4426950408889634f); }
__device__ __forceinline__ float fsigm(float x){ return __builtin_amdgcn_rcpf(1.f + fexp(-x)); }
__device__ __forceinline__ float ftanh(float x){
  float t = __builtin_amdgcn_exp2f(x * 2.8853900817779268f);
  return (t - 1.f) * __builtin_amdgcn_rcpf(t + 1.f);
}
__device__ __forceinline__ float flog(float x){ return __builtin_amdgcn_logf(x) * 0.6931471805599453f; }

// L2 fast-path load: bypass L1 (sc0), hit the XCD-shared L2.
__device__ __forceinline__ u64 ld_l2(const u64* p){
  u64 v;
  asm volatile("global_load_dwordx2 %0, %1, off sc0\n\ts_waitcnt vmcnt(0)"
               : "=v"(v) : "v"(p) : "memory");
  return v;
}
// L2 fast-path store: plain store (lands in the producer XCD's L2).
__device__ __forceinline__ void st_l2(u64* p, u64 v){
  asm volatile("global_store_dwordx2 %0, %1, off" :: "v"(p), "v"(v) : "memory");
}

// ------ fp32 -> bf16 conversions of tables/weights + init duties (merged) ------
__global__ void k_prep(const float* __restrict__ emb, const float* __restrict__ scope,
                       const float* __restrict__ Wih, const float* __restrict__ Wout,
                       const float* __restrict__ Wd,  const float* __restrict__ We,
                       unsigned short* e_o, unsigned short* s_o, unsigned short* wi_o,
                       unsigned short* wo_o, unsigned short* wd_o, unsigned short* we_o,
                       u64* hx, u64* hxL, int* claim, float* out, unsigned short* zbuf){
  int g = blockIdx.x*256 + threadIdx.x, gs = gridDim.x*256;
  if (g < 2*NB*256){
    hx[g] = 0ull;
    __hip_atomic_store(hxL + g, 0ull, __ATOMIC_RELAXED, __HIP_MEMORY_SCOPE_AGENT);
  }
  if (g < 256) __hip_atomic_store(claim + g, 0, __ATOMIC_RELAXED, __HIP_MEMORY_SCOPE_AGENT);
  if (g < NB) out[g] = 0.f;
  if (g < 2048) zbuf[g] = 0;
  for (int i=g; i<NV*NH;      i+=gs) e_o[i]  = f2bf(emb[i]);
  for (int i=g; i<NB*NS*NH;   i+=gs) s_o[i]  = f2bf(scope[i]);
  for (int i=g; i<3*NH*2*NH;  i+=gs) wi_o[i] = f2bf(Wih[i]);
  for (int i=g; i<NV*NH;      i+=gs) wo_o[i] = f2bf(Wout[i]);
  for (int i=g; i<NH*NH;      i+=gs) wd_o[i] = f2bf(Wd[i]);
  for (int i=g; i<NH*NH;      i+=gs) we_o[i] = f2bf(We[i]);
}

// ---------------- h0 = spec_enc @ W_init^T + b_init ----------------------------
// writes f32 copy and tagged packed-f16 exchange words (tag 1, parity-0 buffer)
__global__ void k_h0(const float* __restrict__ spec, const float* __restrict__ Winit,
                     const float* __restrict__ binit, float* __restrict__ h032,
                     u64* __restrict__ hx, u64* __restrict__ hxL){
  const int b = blockIdx.x, tid = threadIdx.x, lane = tid & 63, w = tid >> 6;
  __shared__ float sp[NH];
  __shared__ float hres[NH];
  if (tid < 128) *(float4*)&sp[tid*4] = *(const float4*)(spec + b*NH + tid*4);
  __syncthreads();
  for (int i = 0; i < 128; ++i){
    int j = w * 128 + i;
    const float4* wr = (const float4*)(Winit + (size_t)j * NH);
    float4 x0 = wr[lane*2], x1 = wr[lane*2 + 1];
    float p = x0.x*sp[lane*8]   + x0.y*sp[lane*8+1] + x0.z*sp[lane*8+2] + x0.w*sp[lane*8+3]
            + x1.x*sp[lane*8+4] + x1.y*sp[lane*8+5] + x1.z*sp[lane*8+6] + x1.w*sp[lane*8+7];
    #pragma unroll
    for (int o = 1; o < 64; o <<= 1) p += __shfl_xor(p, o);
    if (lane == 0){
      float v = p + binit[j];
      h032[b*NH + j] = v;
      hres[j] = v;
    }
  }
  __syncthreads();
  if (tid < 256){
    unsigned int pw = __builtin_bit_cast(unsigned int, pkrtz(hres[2*tid], hres[2*tid+1]));
    u64 pv = (1ull << 32) | (u64)pw;           // tag(h_0) = 1
    __hip_atomic_store(hx + b*256 + tid, pv, __ATOMIC_RELAXED, __HIP_MEMORY_SCOPE_AGENT);
    __hip_atomic_store(hxL + b*256 + tid, pv, __ATOMIC_RELAXED, __HIP_MEMORY_SCOPE_AGENT);
  }
}

// ---------------- MFMA bf16 GEMM: C = A @ Bw^T (+bias), 128x128 tile -----------
struct GatherArgs {
  const int* tok; const int* pid; const int* msk;
  const unsigned short* emb; const unsigned short* scope; const unsigned short* zbuf;
};

template<int ASRC>
__global__ __launch_bounds__(256, 2) void k_gemm(
    const unsigned short* __restrict__ A, const unsigned short* __restrict__ Bw,
    float* __restrict__ Cf, unsigned short* __restrict__ Cbf,
    const float* __restrict__ bias, int M, int N, int K, GatherArgs ga)
{
  __shared__ unsigned short lA[2][128][64];
  __shared__ unsigned short lB[2][128][64];
  const int tid = threadIdx.x, lane = tid & 63, wv = tid >> 6;
  const int m0 = blockIdx.x * 128, n0 = blockIdx.y * 128;

  const unsigned short* srcA[4];
  const unsigned short* srcO[4];
  const unsigned short* srcB[4];
  #pragma unroll
  for (int i = 0; i < 4; ++i){
    int ar = m0 + wv*32 + i*8 + (lane >> 3);
    int chunk = (lane & 7) * 8;
    if (ASRC == 0){
      srcA[i] = A + (size_t)ar * K + chunk;
      srcO[i] = nullptr;
    } else {
      int tk = ga.tok[ar], pd = ga.pid[ar], mk = ga.msk[ar];
      srcA[i] = ga.emb + (size_t)tk * NH + chunk;
      srcO[i] = mk ? (ga.scope + ((size_t)((ar >> 8) * NS + pd)) * NH + chunk)
                   : (ga.zbuf + chunk);
    }
    int br = n0 + wv*32 + i*8 + (lane >> 3);
    srcB[i] = Bw + (size_t)br * K + chunk;
  }

  f32x4 acc[4][4];
  #pragma unroll
  for (int x=0;x<4;++x)
    #pragma unroll
    for (int y=0;y<4;++y) acc[x][y] = (f32x4){0.f,0.f,0.f,0.f};

  auto STAGE = [&](int bf, int kt){
    const int k0 = kt * 64;
    #pragma unroll
    for (int i = 0; i < 4; ++i){
      const unsigned short* pa;
      if (ASRC == 0) pa = srcA[i] + k0;
      else pa = (k0 < NH) ? (srcA[i] + k0) : (srcO[i] + (k0 - NH));
      ASYNC16(pa, &lA[bf][wv*32 + i*8][0]);
      ASYNC16(srcB[i] + k0, &lB[bf][wv*32 + i*8][0]);
    }
  };

  STAGE(0, 0);
  asm volatile("s_waitcnt vmcnt(0)" ::: "memory");
  __syncthreads();

  const int wm = (wv >> 1) * 64, wn = (wv & 1) * 64;
  const int fr = lane & 15, fq = lane >> 4;
  const int nt = K >> 6;
  int cur = 0;
  for (int kt = 0; kt < nt; ++kt){
    if (kt + 1 < nt) STAGE(cur ^ 1, kt + 1);
    #pragma unroll
    for (int ks = 0; ks < 2; ++ks){
      bf16x8 af[4], bfv[4];
      #pragma unroll
      for (int mi = 0; mi < 4; ++mi)
        af[mi] = *(const bf16x8*)&lA[cur][wm + mi*16 + fr][ks*32 + fq*8];
      #pragma unroll
      for (int ni = 0; ni < 4; ++ni)
        bfv[ni] = *(const bf16x8*)&lB[cur][wn + ni*16 + fr][ks*32 + fq*8];
      #pragma unroll
      for (int mi = 0; mi < 4; ++mi)
        #pragma unroll
        for (int ni = 0; ni < 4; ++ni)
          acc[mi][ni] = __builtin_amdgcn_mfma_f32_16x16x32_bf16(af[mi], bfv[ni], acc[mi][ni], 0, 0, 0);
    }
    asm volatile("s_waitcnt vmcnt(0)" ::: "memory");
    __syncthreads();
    cur ^= 1;
  }

  #pragma unroll
  for (int mi = 0; mi < 4; ++mi){
    #pragma unroll
    for (int ni = 0; ni < 4; ++ni){
      int col = n0 + wn + ni*16 + fr;
      float bv = bias ? bias[col] : 0.f;
      #pragma unroll
      for (int rr = 0; rr < 4; ++rr){
        int row = m0 + wm + mi*16 + fq*4 + rr;
        float v = acc[mi][ni][rr] + bv;
        if (Cbf) Cbf[(size_t)row * N + col] = f2bf(v);
        else     Cf [(size_t)row * N + col] = v;
      }
    }
  }
}

// ---------------- persistent GRU: 32 batches x 8 slices, 512 thr ---------------
// R9: runtime XCD-claimed slots. Each block reads its ACTUAL XCC_ID and CAS-
// claims a slot, preferring its own XCD's 32 slots; slot -> (batch,slice) such
// that one XCD's 32 slots = 4 whole batches. So batch slices are co-located on
// one XCD whenever claims land locally (by construction, not heuristic), and
// the exchange rides the XCD-shared L2. MALL path backs any cross-XCD case.
__global__ __launch_bounds__(512, 1) void k_gru(
    const float* __restrict__ Whh, const float* __restrict__ bhh,
    const unsigned short* __restrict__ xp,
    const float* __restrict__ h032,
    u64* __restrict__ hx,                 // [2][NB][256] tagged pairs (MALL)
    u64* __restrict__ hxL,                // [2][NB][256] tagged pairs (L2 fast)
    int* __restrict__ claim,              // [256] slot claim table
    unsigned short* __restrict__ obf)
{
  const int tid = threadIdx.x;
  __shared__ int slotS;
  if (tid == 0){
    unsigned int xcd;
    asm volatile("s_getreg_b32 %0, hwreg(HW_REG_XCC_ID)" : "=s"(xcd));
    xcd &= 7;
    int slot = -1;
    for (int i = 0; i < 256; ++i){
      int cand = (int)((xcd << 5) + i) & 255;
      if (atomicCAS(claim + cand, 0, 1) == 0){ slot = cand; break; }
    }
    slotS = slot;
  }
  __syncthreads();
  const int slot = slotS;
  const int b = ((slot >> 5) << 2) + ((slot >> 3) & 3);  // XCD's 4 batches
  const int s = slot & 7;
  const int u = tid >> 3, r = tid & 7;
  const int jg = s * 64 + u;

  __shared__ __align__(16) unsigned int hl[256];   // 512 halfs of h_t
  __shared__ float xpl[192];
  __shared__ unsigned int pkb[32];   // own slice packed bf16 pairs (for obf)

  half2v w0[8][4], w1[8][4], w2[8][4];
  #pragma unroll
  for (int c = 0; c < 8; ++c){
    const int kb = r*64 + ((c + r) & 7) * 8;
    const float* p0 = Whh + ((size_t)(       jg)) * NH + kb;
    const float* p1 = Whh + ((size_t)(  NH + jg)) * NH + kb;
    const float* p2 = Whh + ((size_t)(2*NH + jg)) * NH + kb;
    #pragma unroll
    for (int p = 0; p < 4; ++p){
      float2 a = *(const float2*)(p0 + 2*p);
      float2 c2 = *(const float2*)(p1 + 2*p);
      float2 d = *(const float2*)(p2 + 2*p);
      w0[c][p] = pkrtz(a.x, a.y);
      w1[c][p] = pkrtz(c2.x, c2.y);
      w2[c][p] = pkrtz(d.x, d.y);
    }
  }
  const float bh0 = bhh[jg], bh1 = bhh[NH + jg], bh2 = bhh[2*NH + jg];
  float hprev = h032[b*NH + jg];   // meaningful on r==0 lanes only

  // prime xp double-buffer for t=0 (waves 4-6)
  unsigned short xpv = 0;
  if (tid >= 256 && tid < 448){
    int idx = tid - 256;
    xpv = xp[((size_t)(b*NT + 0)) * 1536 + (idx >> 6) * NH + s*64 + (idx & 63)];
  }
  __syncthreads();

  for (int t = 0; t < NT; ++t){
    if (tid < 256){
      const int base = (((t & 1) * NB + b) << 8) + tid;
      const unsigned int want = (unsigned int)(t + 1);
      u64 v; int it = 0;
      while (true){
        v = ld_l2(hxL + base);                                   // XCD-L2 fast
        if ((unsigned int)(v >> 32) == want) break;
        if ((++it & 3) == 0){
          v = __hip_atomic_load(hx + base, __ATOMIC_RELAXED,     // MALL correct
                                __HIP_MEMORY_SCOPE_AGENT);
          if ((unsigned int)(v >> 32) == want) break;
        }
      }
      hl[tid] = (unsigned int)v;
    } else if (tid < 448){
      int idx = tid - 256;
      xpl[idx] = bf2f(xpv);              // consume prefetched slice (step t)
      if (t + 1 < NT)                     // issue prefetch for step t+1
        xpv = xp[((size_t)(b*NT + t + 1)) * 1536 + (idx >> 6) * NH + s*64 + (idx & 63)];
    }
    __syncthreads();

    // rotated conflict-free chunk loads + 96 fdot2
    float a0 = 0.f, a1 = 0.f, a2 = 0.f;
    half2v hch[8][4];
    #pragma unroll
    for (int c = 0; c < 8; ++c){
      const int g = (r << 3) + ((c + r) & 7);
      uint4 hv = *(const uint4*)&hl[g * 4];
      hch[c][0] = __builtin_bit_cast(half2v, hv.x);
      hch[c][1] = __builtin_bit_cast(half2v, hv.y);
      hch[c][2] = __builtin_bit_cast(half2v, hv.z);
      hch[c][3] = __builtin_bit_cast(half2v, hv.w);
    }
    #pragma unroll
    for (int c = 0; c < 8; ++c){
      #pragma unroll
      for (int p = 0; p < 4; ++p){
        a0 = __builtin_amdgcn_fdot2(w0[c][p], hch[c][p], a0, false);
        a1 = __builtin_amdgcn_fdot2(w1[c][p], hch[c][p], a1, false);
        a2 = __builtin_amdgcn_fdot2(w2[c][p], hch[c][p], a2, false);
      }
    }
    a0 += __shfl_xor(a0, 1); a0 += __shfl_xor(a0, 2); a0 += __shfl_xor(a0, 4);
    a1 += __shfl_xor(a1, 1); a1 += __shfl_xor(a1, 2); a1 += __shfl_xor(a1, 4);
    a2 += __shfl_xor(a2, 1); a2 += __shfl_xor(a2, 2); a2 += __shfl_xor(a2, 4);

    float hnew = 0.f;
    if (r == 0){
      float xr = xpl[u], xz = xpl[64 + u], xn = xpl[128 + u];
      float rg = fsigm(xr + a0 + bh0);
      float zg = fsigm(xz + a1 + bh1);
      float ng = ftanh(xn + rg * (a2 + bh2));
      hnew = (1.f - zg) * ng + zg * hprev;
      hprev = hnew;
    }
    float hpart = __shfl_xor(hnew, 8);   // partner unit u^1 (same r)
    if (r == 0 && (u & 1) == 0){
      unsigned int pw = __builtin_bit_cast(unsigned int, pkrtz(hnew, hpart));
      u64 pv = ((u64)(unsigned int)(t + 2) << 32) | (u64)pw;  // tag(h_{t+1}) = t+2
      const int dst = ((((t + 1) & 1) * NB + b) << 8) + (s << 5) + (u >> 1);
      st_l2(hxL + dst, pv);                                    // fast path first
      __hip_atomic_store(hx + dst, pv,
                         __ATOMIC_RELAXED, __HIP_MEMORY_SCOPE_AGENT);
      pkb[u >> 1] = (unsigned int)f2bf(hnew) | ((unsigned int)f2bf(hpart) << 16);
    }
    __syncthreads();                     // loop-end barrier

    // wave 7 writes obf (coalesced, off the exchange critical path)
    if (tid >= 448 && tid < 480){
      int i = tid - 448;
      ((unsigned int*)obf)[((size_t)(b*NT + t)) * (NH/2) + s*32 + i] = pkb[i];
    }
  }
}

// ---------------- token log-likelihood: sum_t logp[target] --------------------
__global__ void k_tokll(const float* __restrict__ logits, const int* __restrict__ tko,
                        float* __restrict__ out){
  const int tid = threadIdx.x, lane = tid & 63, w = tid >> 6;
  const int r0 = blockIdx.x * 64 + w * 16;
  const int b = r0 >> 8;
  int mytok = 0; float tval = 0.f;
  if (lane < 16){
    mytok = tko[r0 + lane];
    tval = logits[(size_t)(r0 + lane) * NV + mytok];
  }
  float acc = 0.f;
  for (int i = 0; i < 16; ++i){
    const float* L = logits + (size_t)(r0 + i) * NV;
    float l0 = L[lane], l1 = L[64 + lane];
    float m = fmaxf(l0, l1);
    #pragma unroll
    for (int o = 1; o < 64; o <<= 1) m = fmaxf(m, __shfl_xor(m, o));
    float sm = fexp(l0 - m) + fexp(l1 - m);
    #pragma unroll
    for (int o = 1; o < 64; o <<= 1) sm += __shfl_xor(sm, o);
    float lse = m + flog(sm);
    float tv = __shfl(tval, i);
    if (lane == 0) acc += tv - lse;
  }
  if (lane == 0) atomicAdd(out + b, acc);
}

// ---------------- pointer attention + masked log-softmax gather ----------------
__global__ __launch_bounds__(256, 2) void k_ptr(
    const unsigned short* __restrict__ hd, const float* __restrict__ okp,
    const float* __restrict__ vat, const int* __restrict__ ptg,
    const int* __restrict__ pmask, float* __restrict__ out)
{
  __shared__ unsigned short okl[NS][518];
  __shared__ unsigned short hdl[16][518];
  __shared__ float vl[NH];
  __shared__ float attl[16][33];
  const int tid = threadIdx.x;
  const int b = blockIdx.x >> 4, t0 = (blockIdx.x & 15) * 16;
  for (int ii = 0; ii < 64; ++ii){
    int lin = ii*256 + tid;
    int s = lin >> 9, h = lin & 511;
    okl[s][h] = f2bf(okp[((size_t)(b*NS + s)) * NH + h]);
  }
  for (int ii = 0; ii < 32; ++ii){
    int lin = ii*256 + tid;
    int tt = lin >> 9, h = lin & 511;
    hdl[tt][h] = hd[((size_t)(b*NT + t0 + tt)) * NH + h];
  }
  vl[tid] = vat[tid]; vl[256 + tid] = vat[256 + tid];
  __syncthreads();
  #pragma unroll
  for (int pp = 0; pp < 2; ++pp){
    int p = pp*256 + tid;
    int tt = p >> 5, s = p & 31;
    float a = 0.f;
    #pragma unroll 4
    for (int h = 0; h < NH; ++h)
      a += vl[h] * ftanh(bf2f(hdl[tt][h]) + bf2f(okl[s][h]));
    attl[tt][s] = a;
  }
  __syncthreads();
  if (tid < 16){
    int tt = tid;
    float m = -1e30f;
    for (int s = 0; s < NS; ++s) m = fmaxf(m, attl[tt][s]);
    float sm = 0.f;
    for (int s = 0; s < NS; ++s) sm += fexp(attl[tt][s] - m);
    float lse = m + flog(sm);
    int g = b*NT + t0 + tt;
    float c = pmask[g] ? (attl[tt][ptg[g]] - lse) : 0.f;
    #pragma unroll
    for (int o = 1; o < 16; o <<= 1) c += __shfl_xor(c, o);
    if (tid == 0) atomicAdd(out + b, c);
  }
}

// ------------------------------- launch ---------------------------------------
extern "C" void kernel_launch(void* const* d_in, const int* in_sizes, int n_in,
                              void* d_out, int out_size, void* d_ws, size_t ws_size,
                              hipStream_t stream)
{
  (void)in_sizes; (void)n_in; (void)out_size; (void)ws_size;
  const float* embedding  = (const float*)d_in[0];
  const float* scope_enc  = (const float*)d_in[1];
  const float* spec_enc   = (const float*)d_in[2];
  const float* W_init     = (const float*)d_in[3];
  const float* b_init     = (const float*)d_in[4];
  const float* W_ih       = (const float*)d_in[5];
  const float* W_hh       = (const float*)d_in[6];
  const float* b_ih       = (const float*)d_in[7];
  const float* b_hh       = (const float*)d_in[8];
  const float* W_out      = (const float*)d_in[9];
  const float* b_out      = (const float*)d_in[10];
  const float* Wd         = (const float*)d_in[11];
  const float* We         = (const float*)d_in[12];
  const float* v_attn     = (const float*)d_in[13];
  const int* tokens_in    = (const int*)d_in[14];
  const int* tokens_out   = (const int*)d_in[15];
  const int* pointer_ids  = (const int*)d_in[16];
  const int* ptr_targets  = (const int*)d_in[17];
  const int* pointer_mask = (const int*)d_in[18];
  float* outF = (float*)d_out;

  uint8_t* wp = (uint8_t*)d_ws;
  auto carve = [&](size_t bytes)->void*{
    void* p = (void*)wp; wp += (bytes + 255) & ~(size_t)255; return p;
  };
  unsigned short* xp_bf    = (unsigned short*)carve((size_t)BT*1536*2);
  unsigned short* o_bf     = (unsigned short*)carve((size_t)BT*NH*2);
  float*          logitsF  = (float*)carve((size_t)BT*NV*4);
  unsigned short* hd_bf    = (unsigned short*)carve((size_t)BT*NH*2);
  float*          okp      = (float*)carve((size_t)NB*NS*NH*4);
  unsigned short* emb_bf   = (unsigned short*)carve((size_t)NV*NH*2);
  unsigned short* scope_bf = (unsigned short*)carve((size_t)NB*NS*NH*2);
  unsigned short* Wih_bf   = (unsigned short*)carve((size_t)3*NH*2*NH*2);
  unsigned short* Wout_bf  = (unsigned short*)carve((size_t)NV*NH*2);
  unsigned short* Wd_bf    = (unsigned short*)carve((size_t)NH*NH*2);
  unsigned short* We_bf    = (unsigned short*)carve((size_t)NH*NH*2);
  float*          h032     = (float*)carve((size_t)NB*NH*4);
  u64*            hx       = (u64*)carve((size_t)2*NB*256*8);
  u64*            hxL      = (u64*)carve((size_t)2*NB*256*8);
  int*            claim    = (int*)carve(1024);
  unsigned short* zbuf     = (unsigned short*)carve(4096);

  hipLaunchKernelGGL(k_prep, dim3(1024), dim3(256), 0, stream,
                     embedding, scope_enc, W_ih, W_out, Wd, We,
                     emb_bf, scope_bf, Wih_bf, Wout_bf, Wd_bf, We_bf,
                     hx, hxL, claim, outF, zbuf);
  hipLaunchKernelGGL(k_h0, dim3(NB), dim3(256), 0, stream, spec_enc, W_init, b_init,
                     h032, hx, hxL);
  GatherArgs ga{tokens_in, pointer_ids, pointer_mask, emb_bf, scope_bf, zbuf};
  GatherArgs g0{nullptr,nullptr,nullptr,nullptr,nullptr,nullptr};
  // x_proj = [emb|obj] @ W_ih^T + b_ih  -> bf16
  hipLaunchKernelGGL((k_gemm<1>), dim3(64,12), dim3(256), 0, stream,
                     (const unsigned short*)nullptr, Wih_bf, (float*)nullptr, xp_bf,
                     b_ih, BT, 1536, 1024, ga);
  // GRU scan (persistent, 256 blocks x 512 threads)
  hipLaunchKernelGGL(k_gru, dim3(256), dim3(512), 0, stream,
                     W_hh, b_hh, xp_bf, h032, hx, hxL, claim, o_bf);
  // logits = o @ W_out^T + b_out -> f32
  hipLaunchKernelGGL((k_gemm<0>), dim3(64,1), dim3(256), 0, stream,
                     o_bf, Wout_bf, logitsF, (unsigned short*)nullptr, b_out, BT, NV, NH, g0);
  // hd = o @ Wd^T -> bf16
  hipLaunchKernelGGL((k_gemm<0>), dim3(64,4), dim3(256), 0, stream,
                     o_bf, Wd_bf, (float*)nullptr, hd_bf, (const float*)nullptr, BT, NH, NH, g0);
  // ok = scope @ We^T -> f32
  hipLaunchKernelGGL((k_gemm<0>), dim3(8,4), dim3(256), 0, stream,
                     scope_bf, We_bf, okp, (unsigned short*)nullptr, (const float*)nullptr,
                     NB*NS, NH, NH, g0);
  hipLaunchKernelGGL(k_tokll, dim3(128), dim3(256), 0, stream, logitsF, tokens_out, outF);
  hipLaunchKernelGGL(k_ptr, dim3(512), dim3(256), 0, stream,
                     hd_bf, okp, v_attn, ptr_targets, pointer_mask, outF);
}

// Round 10
// 722.288 us; speedup vs baseline: 1.1298x; 1.1298x over previous
//
#include <hip/hip_runtime.h>
#include <stdint.h>

#define NB 32      // B
#define NT 256     // T
#define NS 32      // S
#define NH 512     // H
#define NV 128     // V
#define BT 8192    // B*T

typedef __attribute__((ext_vector_type(8))) __bf16 bf16x8;
typedef __attribute__((ext_vector_type(4))) float f32x4;
typedef __attribute__((ext_vector_type(2))) _Float16 half2v;
typedef unsigned long long u64;

typedef __attribute__((address_space(1))) const unsigned int GASU;
typedef __attribute__((address_space(3))) unsigned int LASU;
#define ASYNC16(g, l) __builtin_amdgcn_global_load_lds((GASU*)(g), (LASU*)(l), 16, 0, 0)

__device__ __forceinline__ half2v pkrtz(float a, float b){
  return __builtin_bit_cast(half2v, __builtin_amdgcn_cvt_pkrtz(a, b));
}
__device__ __forceinline__ unsigned short f2bf(float f){
  unsigned int u = __builtin_bit_cast(unsigned int, f);
  u += 0x7fffu + ((u >> 16) & 1u);
  return (unsigned short)(u >> 16);
}
__device__ __forceinline__ float bf2f(unsigned short h){
  return __builtin_bit_cast(float, ((unsigned int)h) << 16);
}
__device__ __forceinline__ float fexp(float x){ return __builtin_amdgcn_exp2f(x * 1.4426950408889634f); }
__device__ __forceinline__ float fsigm(float x){ return __builtin_amdgcn_rcpf(1.f + fexp(-x)); }
__device__ __forceinline__ float ftanh(float x){
  float t = __builtin_amdgcn_exp2f(x * 2.8853900817779268f);
  return (t - 1.f) * __builtin_amdgcn_rcpf(t + 1.f);
}
__device__ __forceinline__ float flog(float x){ return __builtin_amdgcn_logf(x) * 0.6931471805599453f; }

// L2 fast-path load: bypass L1 (sc0), hit the XCD-shared L2.
__device__ __forceinline__ u64 ld_l2(const u64* p){
  u64 v;
  asm volatile("global_load_dwordx2 %0, %1, off sc0\n\ts_waitcnt vmcnt(0)"
               : "=v"(v) : "v"(p) : "memory");
  return v;
}
// L2 fast-path store: plain store (lands in the producer XCD's L2).
__device__ __forceinline__ void st_l2(u64* p, u64 v){
  asm volatile("global_store_dwordx2 %0, %1, off" :: "v"(p), "v"(v) : "memory");
}

// barrier WITHOUT the vmcnt(0) drain __syncthreads would emit: LDS visibility
// only (lgkmcnt) + raw s_barrier, fenced against scheduler motion (rule #18).
#define BAR() do{ \
  asm volatile("s_waitcnt lgkmcnt(0)" ::: "memory"); \
  __builtin_amdgcn_sched_barrier(0); \
  __builtin_amdgcn_s_barrier(); \
  __builtin_amdgcn_sched_barrier(0); \
}while(0)

// ------ fp32 -> bf16 conversions of tables/weights + init duties (merged) ------
__global__ void k_prep(const float* __restrict__ emb, const float* __restrict__ scope,
                       const float* __restrict__ Wih, const float* __restrict__ Wout,
                       const float* __restrict__ Wd,  const float* __restrict__ We,
                       unsigned short* e_o, unsigned short* s_o, unsigned short* wi_o,
                       unsigned short* wo_o, unsigned short* wd_o, unsigned short* we_o,
                       u64* hx, u64* hxL, int* claim, float* out, unsigned short* zbuf){
  int g = blockIdx.x*256 + threadIdx.x, gs = gridDim.x*256;
  if (g < 2*NB*256){
    hx[g] = 0ull;
    __hip_atomic_store(hxL + g, 0ull, __ATOMIC_RELAXED, __HIP_MEMORY_SCOPE_AGENT);
  }
  if (g < 16) __hip_atomic_store(claim + g, 0, __ATOMIC_RELAXED, __HIP_MEMORY_SCOPE_AGENT);
  if (g < NB) out[g] = 0.f;
  if (g < 2048) zbuf[g] = 0;
  for (int i=g; i<NV*NH;      i+=gs) e_o[i]  = f2bf(emb[i]);
  for (int i=g; i<NB*NS*NH;   i+=gs) s_o[i]  = f2bf(scope[i]);
  for (int i=g; i<3*NH*2*NH;  i+=gs) wi_o[i] = f2bf(Wih[i]);
  for (int i=g; i<NV*NH;      i+=gs) wo_o[i] = f2bf(Wout[i]);
  for (int i=g; i<NH*NH;      i+=gs) wd_o[i] = f2bf(Wd[i]);
  for (int i=g; i<NH*NH;      i+=gs) we_o[i] = f2bf(We[i]);
}

// ---------------- h0 = spec_enc @ W_init^T + b_init ----------------------------
__global__ void k_h0(const float* __restrict__ spec, const float* __restrict__ Winit,
                     const float* __restrict__ binit, float* __restrict__ h032,
                     u64* __restrict__ hx, u64* __restrict__ hxL){
  const int b = blockIdx.x, tid = threadIdx.x, lane = tid & 63, w = tid >> 6;
  __shared__ float sp[NH];
  __shared__ float hres[NH];
  if (tid < 128) *(float4*)&sp[tid*4] = *(const float4*)(spec + b*NH + tid*4);
  __syncthreads();
  for (int i = 0; i < 128; ++i){
    int j = w * 128 + i;
    const float4* wr = (const float4*)(Winit + (size_t)j * NH);
    float4 x0 = wr[lane*2], x1 = wr[lane*2 + 1];
    float p = x0.x*sp[lane*8]   + x0.y*sp[lane*8+1] + x0.z*sp[lane*8+2] + x0.w*sp[lane*8+3]
            + x1.x*sp[lane*8+4] + x1.y*sp[lane*8+5] + x1.z*sp[lane*8+6] + x1.w*sp[lane*8+7];
    #pragma unroll
    for (int o = 1; o < 64; o <<= 1) p += __shfl_xor(p, o);
    if (lane == 0){
      float v = p + binit[j];
      h032[b*NH + j] = v;
      hres[j] = v;
    }
  }
  __syncthreads();
  if (tid < 256){
    unsigned int pw = __builtin_bit_cast(unsigned int, pkrtz(hres[2*tid], hres[2*tid+1]));
    u64 pv = (1ull << 32) | (u64)pw;           // tag(h_0) = 1
    __hip_atomic_store(hx + b*256 + tid, pv, __ATOMIC_RELAXED, __HIP_MEMORY_SCOPE_AGENT);
    __hip_atomic_store(hxL + b*256 + tid, pv, __ATOMIC_RELAXED, __HIP_MEMORY_SCOPE_AGENT);
  }
}

// ---------------- MFMA bf16 GEMM: C = A @ Bw^T (+bias), 128x128 tile -----------
struct GatherArgs {
  const int* tok; const int* pid; const int* msk;
  const unsigned short* emb; const unsigned short* scope; const unsigned short* zbuf;
};

template<int ASRC>
__global__ __launch_bounds__(256, 2) void k_gemm(
    const unsigned short* __restrict__ A, const unsigned short* __restrict__ Bw,
    float* __restrict__ Cf, unsigned short* __restrict__ Cbf,
    const float* __restrict__ bias, int M, int N, int K, GatherArgs ga)
{
  __shared__ unsigned short lA[2][128][64];
  __shared__ unsigned short lB[2][128][64];
  const int tid = threadIdx.x, lane = tid & 63, wv = tid >> 6;
  const int m0 = blockIdx.x * 128, n0 = blockIdx.y * 128;

  const unsigned short* srcA[4];
  const unsigned short* srcO[4];
  const unsigned short* srcB[4];
  #pragma unroll
  for (int i = 0; i < 4; ++i){
    int ar = m0 + wv*32 + i*8 + (lane >> 3);
    int chunk = (lane & 7) * 8;
    if (ASRC == 0){
      srcA[i] = A + (size_t)ar * K + chunk;
      srcO[i] = nullptr;
    } else {
      int tk = ga.tok[ar], pd = ga.pid[ar], mk = ga.msk[ar];
      srcA[i] = ga.emb + (size_t)tk * NH + chunk;
      srcO[i] = mk ? (ga.scope + ((size_t)((ar >> 8) * NS + pd)) * NH + chunk)
                   : (ga.zbuf + chunk);
    }
    int br = n0 + wv*32 + i*8 + (lane >> 3);
    srcB[i] = Bw + (size_t)br * K + chunk;
  }

  f32x4 acc[4][4];
  #pragma unroll
  for (int x=0;x<4;++x)
    #pragma unroll
    for (int y=0;y<4;++y) acc[x][y] = (f32x4){0.f,0.f,0.f,0.f};

  auto STAGE = [&](int bf, int kt){
    const int k0 = kt * 64;
    #pragma unroll
    for (int i = 0; i < 4; ++i){
      const unsigned short* pa;
      if (ASRC == 0) pa = srcA[i] + k0;
      else pa = (k0 < NH) ? (srcA[i] + k0) : (srcO[i] + (k0 - NH));
      ASYNC16(pa, &lA[bf][wv*32 + i*8][0]);
      ASYNC16(srcB[i] + k0, &lB[bf][wv*32 + i*8][0]);
    }
  };

  STAGE(0, 0);
  asm volatile("s_waitcnt vmcnt(0)" ::: "memory");
  __syncthreads();

  const int wm = (wv >> 1) * 64, wn = (wv & 1) * 64;
  const int fr = lane & 15, fq = lane >> 4;
  const int nt = K >> 6;
  int cur = 0;
  for (int kt = 0; kt < nt; ++kt){
    if (kt + 1 < nt) STAGE(cur ^ 1, kt + 1);
    #pragma unroll
    for (int ks = 0; ks < 2; ++ks){
      bf16x8 af[4], bfv[4];
      #pragma unroll
      for (int mi = 0; mi < 4; ++mi)
        af[mi] = *(const bf16x8*)&lA[cur][wm + mi*16 + fr][ks*32 + fq*8];
      #pragma unroll
      for (int ni = 0; ni < 4; ++ni)
        bfv[ni] = *(const bf16x8*)&lB[cur][wn + ni*16 + fr][ks*32 + fq*8];
      #pragma unroll
      for (int mi = 0; mi < 4; ++mi)
        #pragma unroll
        for (int ni = 0; ni < 4; ++ni)
          acc[mi][ni] = __builtin_amdgcn_mfma_f32_16x16x32_bf16(af[mi], bfv[ni], acc[mi][ni], 0, 0, 0);
    }
    asm volatile("s_waitcnt vmcnt(0)" ::: "memory");
    __syncthreads();
    cur ^= 1;
  }

  #pragma unroll
  for (int mi = 0; mi < 4; ++mi){
    #pragma unroll
    for (int ni = 0; ni < 4; ++ni){
      int col = n0 + wn + ni*16 + fr;
      float bv = bias ? bias[col] : 0.f;
      #pragma unroll
      for (int rr = 0; rr < 4; ++rr){
        int row = m0 + wm + mi*16 + fq*4 + rr;
        float v = acc[mi][ni][rr] + bv;
        if (Cbf) Cbf[(size_t)row * N + col] = f2bf(v);
        else     Cf [(size_t)row * N + col] = v;
      }
    }
  }
}

// ---------------- persistent GRU: 32 batches x 8 slices, 512 thr ---------------
// R10: (1) cheap XCD claim (one atomicAdd/block on per-XCD counters -> all 8
// slices of a batch co-located on one XCD; proof: 256 grants, <=1 per block);
// (2) strict role split: waves 0-3 = PURE pollers (only vmem = poll, so their
// vmcnt(0) never drains store acks); waves 4-7 = compute+store, 2 units/lane
// (192 weight VGPRs), producers store hxL/hx/obf DIRECTLY from registers;
// (3) raw s_barrier + lgkmcnt (no vmcnt drain at barriers). Own-slice words
// short-circuit via LDS. Dual-path hxL(L2)/hx(MALL) keeps correctness if the
// claim lands cross-XCD (G16).
__global__ __launch_bounds__(512, 1) void k_gru(
    const float* __restrict__ Whh, const float* __restrict__ bhh,
    const unsigned short* __restrict__ xp,
    const float* __restrict__ h032,
    u64* __restrict__ hx,                 // [2][NB][256] tagged pairs (MALL)
    u64* __restrict__ hxL,                // [2][NB][256] tagged pairs (L2 fast)
    int* __restrict__ claim,              // [16] per-XCD slot counters
    unsigned short* __restrict__ obf)
{
  const int tid = threadIdx.x;
  __shared__ int slotS;
  if (tid == 0){
    unsigned int xcd;
    asm volatile("s_getreg_b32 %0, hwreg(HW_REG_XCC_ID)" : "=s"(xcd));
    xcd &= 7;
    int slot = -1;
    #pragma unroll 1
    for (int k = 0; k < 16; ++k){
      int x = (int)((xcd + k) & 7);
      int idx = atomicAdd(claim + x, 1);
      if (idx < 32){ slot = x * 32 + idx; break; }
    }
    slotS = slot;
  }
  __syncthreads();
  const int slot = slotS;
  const int b = ((slot >> 5) << 2) + ((slot >> 3) & 3);  // XCD's 4 batches
  const int s = slot & 7;

  __shared__ __align__(16) unsigned int hl[256];   // 512 halfs of h_t

  const int l  = tid - 256;          // compute-lane index (valid if tid>=256)
  const int u0 = l >> 3, r = l & 7;  // 32 unit-pairs x 8 k-octants
  const int jgA = s*64 + u0, jgB = jgA + 32;

  // weights: 2 units x 3 gates x 64 halfs = 192 packed VGPRs (compute waves)
  half2v wA0[8][4], wA1[8][4], wA2[8][4], wB0[8][4], wB1[8][4], wB2[8][4];
  if (tid >= 256){
    #pragma unroll
    for (int c = 0; c < 8; ++c){
      const int kb = r*64 + ((c + r) & 7) * 8;
      const float* pA0 = Whh + ((size_t)(       jgA)) * NH + kb;
      const float* pA1 = Whh + ((size_t)(  NH + jgA)) * NH + kb;
      const float* pA2 = Whh + ((size_t)(2*NH + jgA)) * NH + kb;
      const float* pB0 = Whh + ((size_t)(       jgB)) * NH + kb;
      const float* pB1 = Whh + ((size_t)(  NH + jgB)) * NH + kb;
      const float* pB2 = Whh + ((size_t)(2*NH + jgB)) * NH + kb;
      #pragma unroll
      for (int p = 0; p < 4; ++p){
        float2 a0 = *(const float2*)(pA0 + 2*p);
        float2 a1 = *(const float2*)(pA1 + 2*p);
        float2 a2 = *(const float2*)(pA2 + 2*p);
        float2 b0 = *(const float2*)(pB0 + 2*p);
        float2 b1 = *(const float2*)(pB1 + 2*p);
        float2 b2 = *(const float2*)(pB2 + 2*p);
        wA0[c][p] = pkrtz(a0.x, a0.y);
        wA1[c][p] = pkrtz(a1.x, a1.y);
        wA2[c][p] = pkrtz(a2.x, a2.y);
        wB0[c][p] = pkrtz(b0.x, b0.y);
        wB1[c][p] = pkrtz(b1.x, b1.y);
        wB2[c][p] = pkrtz(b2.x, b2.y);
      }
    }
  }
  float bhA0=0.f,bhA1=0.f,bhA2=0.f,bhB0=0.f,bhB1=0.f,bhB2=0.f;
  float hprevA=0.f, hprevB=0.f;
  unsigned short xA0=0,xA1=0,xA2=0,xB0=0,xB1=0,xB2=0;
  if (tid >= 256 && r == 0){
    bhA0 = bhh[jgA]; bhA1 = bhh[NH + jgA]; bhA2 = bhh[2*NH + jgA];
    bhB0 = bhh[jgB]; bhB1 = bhh[NH + jgB]; bhB2 = bhh[2*NH + jgB];
    hprevA = h032[b*NH + jgA]; hprevB = h032[b*NH + jgB];
    const unsigned short* xpb = xp + (size_t)(b*NT + 0) * 1536;
    xA0 = xpb[jgA]; xA1 = xpb[NH + jgA]; xA2 = xpb[2*NH + jgA];
    xB0 = xpb[jgB]; xB1 = xpb[NH + jgB]; xB2 = xpb[2*NH + jgB];
  }
  // prime own-slice hl words from k_h0 output (parity 0)
  if (tid < 256 && (tid >> 5) == s)
    hl[tid] = (unsigned int)hx[((size_t)b << 8) + tid];
  __syncthreads();

  for (int t = 0; t < NT; ++t){
    // waves 0-3: poll remote words (tag == t+1); vmcnt stays poll-only
    if (tid < 256 && (tid >> 5) != s){
      const int base = (((t & 1) * NB + b) << 8) + tid;
      const unsigned int want = (unsigned int)(t + 1);
      u64 v;
      while (true){
        v = ld_l2(hxL + base);                                   // XCD-L2 fast
        if ((unsigned int)(v >> 32) == want) break;
        v = __hip_atomic_load(hx + base, __ATOMIC_RELAXED,       // MALL correct
                              __HIP_MEMORY_SCOPE_AGENT);
        if ((unsigned int)(v >> 32) == want) break;
      }
      hl[tid] = (unsigned int)v;
    }
    BAR();

    u64 wdA = 0, wdB = 0;
    if (tid >= 256){
      float aA0=0.f,aA1=0.f,aA2=0.f,aB0=0.f,aB1=0.f,aB2=0.f;
      #pragma unroll
      for (int c = 0; c < 8; ++c){
        const int g = (r << 3) + ((c + r) & 7);
        uint4 hv = *(const uint4*)&hl[g * 4];
        half2v h0 = __builtin_bit_cast(half2v, hv.x);
        half2v h1 = __builtin_bit_cast(half2v, hv.y);
        half2v h2 = __builtin_bit_cast(half2v, hv.z);
        half2v h3 = __builtin_bit_cast(half2v, hv.w);
        aA0 = __builtin_amdgcn_fdot2(wA0[c][0], h0, aA0, false);
        aA0 = __builtin_amdgcn_fdot2(wA0[c][1], h1, aA0, false);
        aA0 = __builtin_amdgcn_fdot2(wA0[c][2], h2, aA0, false);
        aA0 = __builtin_amdgcn_fdot2(wA0[c][3], h3, aA0, false);
        aA1 = __builtin_amdgcn_fdot2(wA1[c][0], h0, aA1, false);
        aA1 = __builtin_amdgcn_fdot2(wA1[c][1], h1, aA1, false);
        aA1 = __builtin_amdgcn_fdot2(wA1[c][2], h2, aA1, false);
        aA1 = __builtin_amdgcn_fdot2(wA1[c][3], h3, aA1, false);
        aA2 = __builtin_amdgcn_fdot2(wA2[c][0], h0, aA2, false);
        aA2 = __builtin_amdgcn_fdot2(wA2[c][1], h1, aA2, false);
        aA2 = __builtin_amdgcn_fdot2(wA2[c][2], h2, aA2, false);
        aA2 = __builtin_amdgcn_fdot2(wA2[c][3], h3, aA2, false);
        aB0 = __builtin_amdgcn_fdot2(wB0[c][0], h0, aB0, false);
        aB0 = __builtin_amdgcn_fdot2(wB0[c][1], h1, aB0, false);
        aB0 = __builtin_amdgcn_fdot2(wB0[c][2], h2, aB0, false);
        aB0 = __builtin_amdgcn_fdot2(wB0[c][3], h3, aB0, false);
        aB1 = __builtin_amdgcn_fdot2(wB1[c][0], h0, aB1, false);
        aB1 = __builtin_amdgcn_fdot2(wB1[c][1], h1, aB1, false);
        aB1 = __builtin_amdgcn_fdot2(wB1[c][2], h2, aB1, false);
        aB1 = __builtin_amdgcn_fdot2(wB1[c][3], h3, aB1, false);
        aB2 = __builtin_amdgcn_fdot2(wB2[c][0], h0, aB2, false);
        aB2 = __builtin_amdgcn_fdot2(wB2[c][1], h1, aB2, false);
        aB2 = __builtin_amdgcn_fdot2(wB2[c][2], h2, aB2, false);
        aB2 = __builtin_amdgcn_fdot2(wB2[c][3], h3, aB2, false);
      }
      aA0 += __shfl_xor(aA0, 1); aA0 += __shfl_xor(aA0, 2); aA0 += __shfl_xor(aA0, 4);
      aA1 += __shfl_xor(aA1, 1); aA1 += __shfl_xor(aA1, 2); aA1 += __shfl_xor(aA1, 4);
      aA2 += __shfl_xor(aA2, 1); aA2 += __shfl_xor(aA2, 2); aA2 += __shfl_xor(aA2, 4);
      aB0 += __shfl_xor(aB0, 1); aB0 += __shfl_xor(aB0, 2); aB0 += __shfl_xor(aB0, 4);
      aB1 += __shfl_xor(aB1, 1); aB1 += __shfl_xor(aB1, 2); aB1 += __shfl_xor(aB1, 4);
      aB2 += __shfl_xor(aB2, 1); aB2 += __shfl_xor(aB2, 2); aB2 += __shfl_xor(aB2, 4);

      float hnA = 0.f, hnB = 0.f;
      if (r == 0){
        float rgA = fsigm(bf2f(xA0) + aA0 + bhA0);
        float zgA = fsigm(bf2f(xA1) + aA1 + bhA1);
        float ngA = ftanh(bf2f(xA2) + rgA * (aA2 + bhA2));
        hnA = (1.f - zgA) * ngA + zgA * hprevA; hprevA = hnA;
        float rgB = fsigm(bf2f(xB0) + aB0 + bhB0);
        float zgB = fsigm(bf2f(xB1) + aB1 + bhB1);
        float ngB = ftanh(bf2f(xB2) + rgB * (aB2 + bhB2));
        hnB = (1.f - zgB) * ngB + zgB * hprevB; hprevB = hnB;
      }
      float pA = __shfl_xor(hnA, 8);    // partner unit u0^1 (same r)
      float pB = __shfl_xor(hnB, 8);
      if (r == 0 && (u0 & 1) == 0){
        unsigned int uwA = __builtin_bit_cast(unsigned int, pkrtz(hnA, pA));
        unsigned int uwB = __builtin_bit_cast(unsigned int, pkrtz(hnB, pB));
        const u64 tg = (u64)(unsigned int)(t + 2) << 32;
        wdA = tg | (u64)uwA;
        wdB = tg | (u64)uwB;
        const int pb = (((t + 1) & 1) * NB + b) << 8;
        const int jA = (s << 5) + (u0 >> 1), jB = jA + 16;
        st_l2(hxL + pb + jA, wdA);
        st_l2(hxL + pb + jB, wdB);
        __hip_atomic_store(hx + pb + jA, wdA, __ATOMIC_RELAXED, __HIP_MEMORY_SCOPE_AGENT);
        __hip_atomic_store(hx + pb + jB, wdB, __ATOMIC_RELAXED, __HIP_MEMORY_SCOPE_AGENT);
        unsigned int obA = (unsigned int)f2bf(hnA) | ((unsigned int)f2bf(pA) << 16);
        unsigned int obB = (unsigned int)f2bf(hnB) | ((unsigned int)f2bf(pB) << 16);
        ((unsigned int*)obf)[(size_t)(b*NT + t) * (NH/2) + jA - (s << 5) + s*32] = obA;
        ((unsigned int*)obf)[(size_t)(b*NT + t) * (NH/2) + jB - (s << 5) + s*32] = obB;
      }
    }
    BAR();
    // own-slice hl words for step t+1 (local short-circuit, no global RT)
    if (tid >= 256 && r == 0 && (u0 & 1) == 0){
      hl[(s << 5) + (u0 >> 1)]      = (unsigned int)wdA;
      hl[(s << 5) + 16 + (u0 >> 1)] = (unsigned int)wdB;
    }
    // xp prefetch for t+1 (compute waves; ack wait lands before next gates)
    if (tid >= 256 && r == 0 && t + 1 < NT){
      const unsigned short* xpb = xp + (size_t)(b*NT + t + 1) * 1536;
      xA0 = xpb[jgA]; xA1 = xpb[NH + jgA]; xA2 = xpb[2*NH + jgA];
      xB0 = xpb[jgB]; xB1 = xpb[NH + jgB]; xB2 = xpb[2*NH + jgB];
    }
  }
}

// ---------------- token log-likelihood: sum_t logp[target] --------------------
__global__ void k_tokll(const float* __restrict__ logits, const int* __restrict__ tko,
                        float* __restrict__ out){
  const int tid = threadIdx.x, lane = tid & 63, w = tid >> 6;
  const int r0 = blockIdx.x * 64 + w * 16;
  const int b = r0 >> 8;
  int mytok = 0; float tval = 0.f;
  if (lane < 16){
    mytok = tko[r0 + lane];
    tval = logits[(size_t)(r0 + lane) * NV + mytok];
  }
  float acc = 0.f;
  for (int i = 0; i < 16; ++i){
    const float* L = logits + (size_t)(r0 + i) * NV;
    float l0 = L[lane], l1 = L[64 + lane];
    float m = fmaxf(l0, l1);
    #pragma unroll
    for (int o = 1; o < 64; o <<= 1) m = fmaxf(m, __shfl_xor(m, o));
    float sm = fexp(l0 - m) + fexp(l1 - m);
    #pragma unroll
    for (int o = 1; o < 64; o <<= 1) sm += __shfl_xor(sm, o);
    float lse = m + flog(sm);
    float tv = __shfl(tval, i);
    if (lane == 0) acc += tv - lse;
  }
  if (lane == 0) atomicAdd(out + b, acc);
}

// ---------------- pointer attention + masked log-softmax gather ----------------
__global__ __launch_bounds__(256, 2) void k_ptr(
    const unsigned short* __restrict__ hd, const float* __restrict__ okp,
    const float* __restrict__ vat, const int* __restrict__ ptg,
    const int* __restrict__ pmask, float* __restrict__ out)
{
  __shared__ unsigned short okl[NS][518];
  __shared__ unsigned short hdl[16][518];
  __shared__ float vl[NH];
  __shared__ float attl[16][33];
  const int tid = threadIdx.x;
  const int b = blockIdx.x >> 4, t0 = (blockIdx.x & 15) * 16;
  for (int ii = 0; ii < 64; ++ii){
    int lin = ii*256 + tid;
    int s = lin >> 9, h = lin & 511;
    okl[s][h] = f2bf(okp[((size_t)(b*NS + s)) * NH + h]);
  }
  for (int ii = 0; ii < 32; ++ii){
    int lin = ii*256 + tid;
    int tt = lin >> 9, h = lin & 511;
    hdl[tt][h] = hd[((size_t)(b*NT + t0 + tt)) * NH + h];
  }
  vl[tid] = vat[tid]; vl[256 + tid] = vat[256 + tid];
  __syncthreads();
  #pragma unroll
  for (int pp = 0; pp < 2; ++pp){
    int p = pp*256 + tid;
    int tt = p >> 5, s = p & 31;
    float a = 0.f;
    #pragma unroll 4
    for (int h = 0; h < NH; ++h)
      a += vl[h] * ftanh(bf2f(hdl[tt][h]) + bf2f(okl[s][h]));
    attl[tt][s] = a;
  }
  __syncthreads();
  if (tid < 16){
    int tt = tid;
    float m = -1e30f;
    for (int s = 0; s < NS; ++s) m = fmaxf(m, attl[tt][s]);
    float sm = 0.f;
    for (int s = 0; s < NS; ++s) sm += fexp(attl[tt][s] - m);
    float lse = m + flog(sm);
    int g = b*NT + t0 + tt;
    float c = pmask[g] ? (attl[tt][ptg[g]] - lse) : 0.f;
    #pragma unroll
    for (int o = 1; o < 16; o <<= 1) c += __shfl_xor(c, o);
    if (tid == 0) atomicAdd(out + b, c);
  }
}

// ------------------------------- launch ---------------------------------------
extern "C" void kernel_launch(void* const* d_in, const int* in_sizes, int n_in,
                              void* d_out, int out_size, void* d_ws, size_t ws_size,
                              hipStream_t stream)
{
  (void)in_sizes; (void)n_in; (void)out_size; (void)ws_size;
  const float* embedding  = (const float*)d_in[0];
  const float* scope_enc  = (const float*)d_in[1];
  const float* spec_enc   = (const float*)d_in[2];
  const float* W_init     = (const float*)d_in[3];
  const float* b_init     = (const float*)d_in[4];
  const float* W_ih       = (const float*)d_in[5];
  const float* W_hh       = (const float*)d_in[6];
  const float* b_ih       = (const float*)d_in[7];
  const float* b_hh       = (const float*)d_in[8];
  const float* W_out      = (const float*)d_in[9];
  const float* b_out      = (const float*)d_in[10];
  const float* Wd         = (const float*)d_in[11];
  const float* We         = (const float*)d_in[12];
  const float* v_attn     = (const float*)d_in[13];
  const int* tokens_in    = (const int*)d_in[14];
  const int* tokens_out   = (const int*)d_in[15];
  const int* pointer_ids  = (const int*)d_in[16];
  const int* ptr_targets  = (const int*)d_in[17];
  const int* pointer_mask = (const int*)d_in[18];
  float* outF = (float*)d_out;

  uint8_t* wp = (uint8_t*)d_ws;
  auto carve = [&](size_t bytes)->void*{
    void* p = (void*)wp; wp += (bytes + 255) & ~(size_t)255; return p;
  };
  unsigned short* xp_bf    = (unsigned short*)carve((size_t)BT*1536*2);
  unsigned short* o_bf     = (unsigned short*)carve((size_t)BT*NH*2);
  float*          logitsF  = (float*)carve((size_t)BT*NV*4);
  unsigned short* hd_bf    = (unsigned short*)carve((size_t)BT*NH*2);
  float*          okp      = (float*)carve((size_t)NB*NS*NH*4);
  unsigned short* emb_bf   = (unsigned short*)carve((size_t)NV*NH*2);
  unsigned short* scope_bf = (unsigned short*)carve((size_t)NB*NS*NH*2);
  unsigned short* Wih_bf   = (unsigned short*)carve((size_t)3*NH*2*NH*2);
  unsigned short* Wout_bf  = (unsigned short*)carve((size_t)NV*NH*2);
  unsigned short* Wd_bf    = (unsigned short*)carve((size_t)NH*NH*2);
  unsigned short* We_bf    = (unsigned short*)carve((size_t)NH*NH*2);
  float*          h032     = (float*)carve((size_t)NB*NH*4);
  u64*            hx       = (u64*)carve((size_t)2*NB*256*8);
  u64*            hxL      = (u64*)carve((size_t)2*NB*256*8);
  int*            claim    = (int*)carve(1024);
  unsigned short* zbuf     = (unsigned short*)carve(4096);

  hipLaunchKernelGGL(k_prep, dim3(1024), dim3(256), 0, stream,
                     embedding, scope_enc, W_ih, W_out, Wd, We,
                     emb_bf, scope_bf, Wih_bf, Wout_bf, Wd_bf, We_bf,
                     hx, hxL, claim, outF, zbuf);
  hipLaunchKernelGGL(k_h0, dim3(NB), dim3(256), 0, stream, spec_enc, W_init, b_init,
                     h032, hx, hxL);
  GatherArgs ga{tokens_in, pointer_ids, pointer_mask, emb_bf, scope_bf, zbuf};
  GatherArgs g0{nullptr,nullptr,nullptr,nullptr,nullptr,nullptr};
  // x_proj = [emb|obj] @ W_ih^T + b_ih  -> bf16
  hipLaunchKernelGGL((k_gemm<1>), dim3(64,12), dim3(256), 0, stream,
                     (const unsigned short*)nullptr, Wih_bf, (float*)nullptr, xp_bf,
                     b_ih, BT, 1536, 1024, ga);
  // GRU scan (persistent, 256 blocks x 512 threads)
  hipLaunchKernelGGL(k_gru, dim3(256), dim3(512), 0, stream,
                     W_hh, b_hh, xp_bf, h032, hx, hxL, claim, o_bf);
  // logits = o @ W_out^T + b_out -> f32
  hipLaunchKernelGGL((k_gemm<0>), dim3(64,1), dim3(256), 0, stream,
                     o_bf, Wout_bf, logitsF, (unsigned short*)nullptr, b_out, BT, NV, NH, g0);
  // hd = o @ Wd^T -> bf16
  hipLaunchKernelGGL((k_gemm<0>), dim3(64,4), dim3(256), 0, stream,
                     o_bf, Wd_bf, (float*)nullptr, hd_bf, (const float*)nullptr, BT, NH, NH, g0);
  // ok = scope @ We^T -> f32
  hipLaunchKernelGGL((k_gemm<0>), dim3(8,4), dim3(256), 0, stream,
                     scope_bf, We_bf, okp, (unsigned short*)nullptr, (const float*)nullptr,
                     NB*NS, NH, NH, g0);
  hipLaunchKernelGGL(k_tokll, dim3(128), dim3(256), 0, stream, logitsF, tokens_out, outF);
  hipLaunchKernelGGL(k_ptr, dim3(512), dim3(256), 0, stream,
                     hd_bf, okp, v_attn, ptr_targets, pointer_mask, outF);
}

// Round 11
// 645.979 us; speedup vs baseline: 1.2633x; 1.1181x over previous
//
#include <hip/hip_runtime.h>
#include <stdint.h>

#define NB 32      // B
#define NT 256     // T
#define NS 32      // S
#define NH 512     // H
#define NV 128     // V
#define BT 8192    // B*T

typedef __attribute__((ext_vector_type(8))) __bf16 bf16x8;
typedef __attribute__((ext_vector_type(4))) float f32x4;
typedef __attribute__((ext_vector_type(2))) _Float16 half2v;
typedef unsigned long long u64;

typedef __attribute__((address_space(1))) const unsigned int GASU;
typedef __attribute__((address_space(3))) unsigned int LASU;
#define ASYNC16(g, l) __builtin_amdgcn_global_load_lds((GASU*)(g), (LASU*)(l), 16, 0, 0)

__device__ __forceinline__ half2v pkrtz(float a, float b){
  return __builtin_bit_cast(half2v, __builtin_amdgcn_cvt_pkrtz(a, b));
}
__device__ __forceinline__ unsigned short f2bf(float f){
  unsigned int u = __builtin_bit_cast(unsigned int, f);
  u += 0x7fffu + ((u >> 16) & 1u);
  return (unsigned short)(u >> 16);
}
__device__ __forceinline__ float bf2f(unsigned short h){
  return __builtin_bit_cast(float, ((unsigned int)h) << 16);
}
__device__ __forceinline__ float fexp(float x){ return __builtin_amdgcn_exp2f(x * 1.4426950408889634f); }
__device__ __forceinline__ float fsigm(float x){ return __builtin_amdgcn_rcpf(1.f + fexp(-x)); }
__device__ __forceinline__ float ftanh(float x){
  float t = __builtin_amdgcn_exp2f(x * 2.8853900817779268f);
  return (t - 1.f) * __builtin_amdgcn_rcpf(t + 1.f);
}
__device__ __forceinline__ float flog(float x){ return __builtin_amdgcn_logf(x) * 0.6931471805599453f; }

// L2 fast-path store: plain store (lands in the producer XCD's L2).
__device__ __forceinline__ void st_l2(u64* p, u64 v){
  asm volatile("global_store_dwordx2 %0, %1, off" :: "v"(p), "v"(v) : "memory");
}

// barrier WITHOUT the vmcnt(0) drain __syncthreads would emit: LDS visibility
// only (lgkmcnt) + raw s_barrier, fenced against scheduler motion (rule #18).
#define BAR() do{ \
  asm volatile("s_waitcnt lgkmcnt(0)" ::: "memory"); \
  __builtin_amdgcn_sched_barrier(0); \
  __builtin_amdgcn_s_barrier(); \
  __builtin_amdgcn_sched_barrier(0); \
}while(0)

// ------ fp32 -> bf16 conversions of tables/weights + init duties (merged) ------
__global__ void k_prep(const float* __restrict__ emb, const float* __restrict__ scope,
                       const float* __restrict__ Wih, const float* __restrict__ Wout,
                       const float* __restrict__ Wd,  const float* __restrict__ We,
                       unsigned short* e_o, unsigned short* s_o, unsigned short* wi_o,
                       unsigned short* wo_o, unsigned short* wd_o, unsigned short* we_o,
                       u64* hx, u64* hxL, float* out, unsigned short* zbuf){
  int g = blockIdx.x*256 + threadIdx.x, gs = gridDim.x*256;
  if (g < 2*NB*256){
    hx[g] = 0ull;
    __hip_atomic_store(hxL + g, 0ull, __ATOMIC_RELAXED, __HIP_MEMORY_SCOPE_AGENT);
  }
  if (g < NB) out[g] = 0.f;
  if (g < 2048) zbuf[g] = 0;
  for (int i=g; i<NV*NH;      i+=gs) e_o[i]  = f2bf(emb[i]);
  for (int i=g; i<NB*NS*NH;   i+=gs) s_o[i]  = f2bf(scope[i]);
  for (int i=g; i<3*NH*2*NH;  i+=gs) wi_o[i] = f2bf(Wih[i]);
  for (int i=g; i<NV*NH;      i+=gs) wo_o[i] = f2bf(Wout[i]);
  for (int i=g; i<NH*NH;      i+=gs) wd_o[i] = f2bf(Wd[i]);
  for (int i=g; i<NH*NH;      i+=gs) we_o[i] = f2bf(We[i]);
}

// ---------------- h0 = spec_enc @ W_init^T + b_init ----------------------------
// writes f32 copy and tagged packed-f16 exchange words (tag 1, parity-0 buffer)
__global__ void k_h0(const float* __restrict__ spec, const float* __restrict__ Winit,
                     const float* __restrict__ binit, float* __restrict__ h032,
                     u64* __restrict__ hx, u64* __restrict__ hxL){
  const int b = blockIdx.x, tid = threadIdx.x, lane = tid & 63, w = tid >> 6;
  __shared__ float sp[NH];
  __shared__ float hres[NH];
  if (tid < 128) *(float4*)&sp[tid*4] = *(const float4*)(spec + b*NH + tid*4);
  __syncthreads();
  for (int i = 0; i < 128; ++i){
    int j = w * 128 + i;
    const float4* wr = (const float4*)(Winit + (size_t)j * NH);
    float4 x0 = wr[lane*2], x1 = wr[lane*2 + 1];
    float p = x0.x*sp[lane*8]   + x0.y*sp[lane*8+1] + x0.z*sp[lane*8+2] + x0.w*sp[lane*8+3]
            + x1.x*sp[lane*8+4] + x1.y*sp[lane*8+5] + x1.z*sp[lane*8+6] + x1.w*sp[lane*8+7];
    #pragma unroll
    for (int o = 1; o < 64; o <<= 1) p += __shfl_xor(p, o);
    if (lane == 0){
      float v = p + binit[j];
      h032[b*NH + j] = v;
      hres[j] = v;
    }
  }
  __syncthreads();
  if (tid < 256){
    unsigned int pw = __builtin_bit_cast(unsigned int, pkrtz(hres[2*tid], hres[2*tid+1]));
    u64 pv = (1ull << 32) | (u64)pw;           // tag(h_0) = 1
    __hip_atomic_store(hx + b*256 + tid, pv, __ATOMIC_RELAXED, __HIP_MEMORY_SCOPE_AGENT);
    __hip_atomic_store(hxL + b*256 + tid, pv, __ATOMIC_RELAXED, __HIP_MEMORY_SCOPE_AGENT);
  }
}

// ---------------- MFMA bf16 GEMM: C = A @ Bw^T (+bias), 128x128 tile -----------
struct GatherArgs {
  const int* tok; const int* pid; const int* msk;
  const unsigned short* emb; const unsigned short* scope; const unsigned short* zbuf;
};

template<int ASRC>
__global__ __launch_bounds__(256, 2) void k_gemm(
    const unsigned short* __restrict__ A, const unsigned short* __restrict__ Bw,
    float* __restrict__ Cf, unsigned short* __restrict__ Cbf,
    const float* __restrict__ bias, int M, int N, int K, GatherArgs ga)
{
  __shared__ unsigned short lA[2][128][64];
  __shared__ unsigned short lB[2][128][64];
  const int tid = threadIdx.x, lane = tid & 63, wv = tid >> 6;
  const int m0 = blockIdx.x * 128, n0 = blockIdx.y * 128;

  const unsigned short* srcA[4];
  const unsigned short* srcO[4];
  const unsigned short* srcB[4];
  #pragma unroll
  for (int i = 0; i < 4; ++i){
    int ar = m0 + wv*32 + i*8 + (lane >> 3);
    int chunk = (lane & 7) * 8;
    if (ASRC == 0){
      srcA[i] = A + (size_t)ar * K + chunk;
      srcO[i] = nullptr;
    } else {
      int tk = ga.tok[ar], pd = ga.pid[ar], mk = ga.msk[ar];
      srcA[i] = ga.emb + (size_t)tk * NH + chunk;
      srcO[i] = mk ? (ga.scope + ((size_t)((ar >> 8) * NS + pd)) * NH + chunk)
                   : (ga.zbuf + chunk);
    }
    int br = n0 + wv*32 + i*8 + (lane >> 3);
    srcB[i] = Bw + (size_t)br * K + chunk;
  }

  f32x4 acc[4][4];
  #pragma unroll
  for (int x=0;x<4;++x)
    #pragma unroll
    for (int y=0;y<4;++y) acc[x][y] = (f32x4){0.f,0.f,0.f,0.f};

  auto STAGE = [&](int bf, int kt){
    const int k0 = kt * 64;
    #pragma unroll
    for (int i = 0; i < 4; ++i){
      const unsigned short* pa;
      if (ASRC == 0) pa = srcA[i] + k0;
      else pa = (k0 < NH) ? (srcA[i] + k0) : (srcO[i] + (k0 - NH));
      ASYNC16(pa, &lA[bf][wv*32 + i*8][0]);
      ASYNC16(srcB[i] + k0, &lB[bf][wv*32 + i*8][0]);
    }
  };

  STAGE(0, 0);
  asm volatile("s_waitcnt vmcnt(0)" ::: "memory");
  __syncthreads();

  const int wm = (wv >> 1) * 64, wn = (wv & 1) * 64;
  const int fr = lane & 15, fq = lane >> 4;
  const int nt = K >> 6;
  int cur = 0;
  for (int kt = 0; kt < nt; ++kt){
    if (kt + 1 < nt) STAGE(cur ^ 1, kt + 1);
    #pragma unroll
    for (int ks = 0; ks < 2; ++ks){
      bf16x8 af[4], bfv[4];
      #pragma unroll
      for (int mi = 0; mi < 4; ++mi)
        af[mi] = *(const bf16x8*)&lA[cur][wm + mi*16 + fr][ks*32 + fq*8];
      #pragma unroll
      for (int ni = 0; ni < 4; ++ni)
        bfv[ni] = *(const bf16x8*)&lB[cur][wn + ni*16 + fr][ks*32 + fq*8];
      #pragma unroll
      for (int mi = 0; mi < 4; ++mi)
        #pragma unroll
        for (int ni = 0; ni < 4; ++ni)
          acc[mi][ni] = __builtin_amdgcn_mfma_f32_16x16x32_bf16(af[mi], bfv[ni], acc[mi][ni], 0, 0, 0);
    }
    asm volatile("s_waitcnt vmcnt(0)" ::: "memory");
    __syncthreads();
    cur ^= 1;
  }

  #pragma unroll
  for (int mi = 0; mi < 4; ++mi){
    #pragma unroll
    for (int ni = 0; ni < 4; ++ni){
      int col = n0 + wn + ni*16 + fr;
      float bv = bias ? bias[col] : 0.f;
      #pragma unroll
      for (int rr = 0; rr < 4; ++rr){
        int row = m0 + wm + mi*16 + fq*4 + rr;
        float v = acc[mi][ni][rr] + bv;
        if (Cbf) Cbf[(size_t)row * N + col] = f2bf(v);
        else     Cf [(size_t)row * N + col] = v;
      }
    }
  }
}

// ---------------- persistent GRU: 32 batches x 8 slices, 512 thr ---------------
// R11 = R8 base (static bid remap: all 8 slices of batch b at bid≡b mod 8 ->
// same XCD under round-robin; dual-path hxL(L2)/hx(MALL) keeps correctness if
// the mapping fails, G16) + two changes:
//  (1) pipelined 2-deep poll: two loads of the word in flight, check the older
//      while the newer is outstanding (compiler emits vmcnt(1)-style waits).
//      Safe: a matched word cannot be overwritten until this block's poll
//      phase exits (lag-2 impossibility), so unconditional shift is stable.
//  (2) BAR() (lgkmcnt-only raw s_barrier) instead of __syncthreads in the
//      t-loop: producer store-acks no longer gate every wave at the barrier.
__global__ __launch_bounds__(512, 1) void k_gru(
    const float* __restrict__ Whh, const float* __restrict__ bhh,
    const unsigned short* __restrict__ xp,
    const float* __restrict__ h032,
    u64* __restrict__ hx,                 // [2][NB][256] tagged pairs (MALL)
    u64* __restrict__ hxL,                // [2][NB][256] tagged pairs (L2 fast)
    unsigned short* __restrict__ obf)
{
  const int bid = blockIdx.x;
  const int b = bid & 31, s = bid >> 5;   // all slices of batch b on one XCD
  const int tid = threadIdx.x;
  const int u = tid >> 3, r = tid & 7;
  const int jg = s * 64 + u;

  __shared__ __align__(16) unsigned int hl[256];   // 512 halfs of h_t
  __shared__ float xpl[192];
  __shared__ unsigned int pkb[32];   // own slice packed bf16 pairs (for obf)

  half2v w0[8][4], w1[8][4], w2[8][4];
  #pragma unroll
  for (int c = 0; c < 8; ++c){
    const int kb = r*64 + ((c + r) & 7) * 8;
    const float* p0 = Whh + ((size_t)(       jg)) * NH + kb;
    const float* p1 = Whh + ((size_t)(  NH + jg)) * NH + kb;
    const float* p2 = Whh + ((size_t)(2*NH + jg)) * NH + kb;
    #pragma unroll
    for (int p = 0; p < 4; ++p){
      float2 a = *(const float2*)(p0 + 2*p);
      float2 c2 = *(const float2*)(p1 + 2*p);
      float2 d = *(const float2*)(p2 + 2*p);
      w0[c][p] = pkrtz(a.x, a.y);
      w1[c][p] = pkrtz(c2.x, c2.y);
      w2[c][p] = pkrtz(d.x, d.y);
    }
  }
  const float bh0 = bhh[jg], bh1 = bhh[NH + jg], bh2 = bhh[2*NH + jg];
  float hprev = h032[b*NH + jg];   // meaningful on r==0 lanes only

  // prime xp double-buffer for t=0 (waves 4-6)
  unsigned short xpv = 0;
  if (tid >= 256 && tid < 448){
    int idx = tid - 256;
    xpv = xp[((size_t)(b*NT + 0)) * 1536 + (idx >> 6) * NH + s*64 + (idx & 63)];
  }
  __syncthreads();

  for (int t = 0; t < NT; ++t){
    if (tid < 256){
      const int base = (((t & 1) * NB + b) << 8) + tid;
      const u64* pL = hxL + base;
      const u64* pM = hx + base;
      const unsigned int want = (unsigned int)(t + 1);
      u64 v;
      // pipelined 2-deep poll on the L2 copy; MALL fallback every 8th round
      u64 a  = __hip_atomic_load(pL, __ATOMIC_RELAXED, __HIP_MEMORY_SCOPE_AGENT);
      u64 b2 = __hip_atomic_load(pL, __ATOMIC_RELAXED, __HIP_MEMORY_SCOPE_AGENT);
      int it = 0;
      while (true){
        if ((unsigned int)(a >> 32) == want){ v = a; break; }
        a = b2;
        b2 = __hip_atomic_load(pL, __ATOMIC_RELAXED, __HIP_MEMORY_SCOPE_AGENT);
        if (((++it) & 7) == 0){
          u64 m = __hip_atomic_load(pM, __ATOMIC_RELAXED, __HIP_MEMORY_SCOPE_AGENT);
          if ((unsigned int)(m >> 32) == want){ v = m; break; }
        }
      }
      hl[tid] = (unsigned int)v;
    } else if (tid < 448){
      int idx = tid - 256;
      xpl[idx] = bf2f(xpv);              // consume prefetched slice (step t)
      if (t + 1 < NT)                     // issue prefetch for step t+1
        xpv = xp[((size_t)(b*NT + t + 1)) * 1536 + (idx >> 6) * NH + s*64 + (idx & 63)];
    }
    BAR();

    // rotated conflict-free chunk loads + 96 fdot2
    float a0 = 0.f, a1 = 0.f, a2 = 0.f;
    half2v hch[8][4];
    #pragma unroll
    for (int c = 0; c < 8; ++c){
      const int g = (r << 3) + ((c + r) & 7);
      uint4 hv = *(const uint4*)&hl[g * 4];
      hch[c][0] = __builtin_bit_cast(half2v, hv.x);
      hch[c][1] = __builtin_bit_cast(half2v, hv.y);
      hch[c][2] = __builtin_bit_cast(half2v, hv.z);
      hch[c][3] = __builtin_bit_cast(half2v, hv.w);
    }
    #pragma unroll
    for (int c = 0; c < 8; ++c){
      #pragma unroll
      for (int p = 0; p < 4; ++p){
        a0 = __builtin_amdgcn_fdot2(w0[c][p], hch[c][p], a0, false);
        a1 = __builtin_amdgcn_fdot2(w1[c][p], hch[c][p], a1, false);
        a2 = __builtin_amdgcn_fdot2(w2[c][p], hch[c][p], a2, false);
      }
    }
    a0 += __shfl_xor(a0, 1); a0 += __shfl_xor(a0, 2); a0 += __shfl_xor(a0, 4);
    a1 += __shfl_xor(a1, 1); a1 += __shfl_xor(a1, 2); a1 += __shfl_xor(a1, 4);
    a2 += __shfl_xor(a2, 1); a2 += __shfl_xor(a2, 2); a2 += __shfl_xor(a2, 4);

    float hnew = 0.f;
    if (r == 0){
      float xr = xpl[u], xz = xpl[64 + u], xn = xpl[128 + u];
      float rg = fsigm(xr + a0 + bh0);
      float zg = fsigm(xz + a1 + bh1);
      float ng = ftanh(xn + rg * (a2 + bh2));
      hnew = (1.f - zg) * ng + zg * hprev;
      hprev = hnew;
    }
    float hpart = __shfl_xor(hnew, 8);   // partner unit u^1 (same r)
    if (r == 0 && (u & 1) == 0){
      unsigned int pw = __builtin_bit_cast(unsigned int, pkrtz(hnew, hpart));
      u64 pv = ((u64)(unsigned int)(t + 2) << 32) | (u64)pw;  // tag(h_{t+1}) = t+2
      const int dst = ((((t + 1) & 1) * NB + b) << 8) + (s << 5) + (u >> 1);
      st_l2(hxL + dst, pv);                                    // fast path first
      __hip_atomic_store(hx + dst, pv,
                         __ATOMIC_RELAXED, __HIP_MEMORY_SCOPE_AGENT);
      pkb[u >> 1] = (unsigned int)f2bf(hnew) | ((unsigned int)f2bf(hpart) << 16);
    }
    BAR();                               // loop-end barrier (no vmcnt drain)

    // wave 7 writes obf (coalesced, off the exchange critical path)
    if (tid >= 448 && tid < 480){
      int i = tid - 448;
      ((unsigned int*)obf)[((size_t)(b*NT + t)) * (NH/2) + s*32 + i] = pkb[i];
    }
  }
}

// ---------------- token log-likelihood: sum_t logp[target] --------------------
__global__ void k_tokll(const float* __restrict__ logits, const int* __restrict__ tko,
                        float* __restrict__ out){
  const int tid = threadIdx.x, lane = tid & 63, w = tid >> 6;
  const int r0 = blockIdx.x * 64 + w * 16;
  const int b = r0 >> 8;
  int mytok = 0; float tval = 0.f;
  if (lane < 16){
    mytok = tko[r0 + lane];
    tval = logits[(size_t)(r0 + lane) * NV + mytok];
  }
  float acc = 0.f;
  for (int i = 0; i < 16; ++i){
    const float* L = logits + (size_t)(r0 + i) * NV;
    float l0 = L[lane], l1 = L[64 + lane];
    float m = fmaxf(l0, l1);
    #pragma unroll
    for (int o = 1; o < 64; o <<= 1) m = fmaxf(m, __shfl_xor(m, o));
    float sm = fexp(l0 - m) + fexp(l1 - m);
    #pragma unroll
    for (int o = 1; o < 64; o <<= 1) sm += __shfl_xor(sm, o);
    float lse = m + flog(sm);
    float tv = __shfl(tval, i);
    if (lane == 0) acc += tv - lse;
  }
  if (lane == 0) atomicAdd(out + b, acc);
}

// ---------------- pointer attention + masked log-softmax gather ----------------
__global__ __launch_bounds__(256, 2) void k_ptr(
    const unsigned short* __restrict__ hd, const float* __restrict__ okp,
    const float* __restrict__ vat, const int* __restrict__ ptg,
    const int* __restrict__ pmask, float* __restrict__ out)
{
  __shared__ unsigned short okl[NS][518];
  __shared__ unsigned short hdl[16][518];
  __shared__ float vl[NH];
  __shared__ float attl[16][33];
  const int tid = threadIdx.x;
  const int b = blockIdx.x >> 4, t0 = (blockIdx.x & 15) * 16;
  for (int ii = 0; ii < 64; ++ii){
    int lin = ii*256 + tid;
    int s = lin >> 9, h = lin & 511;
    okl[s][h] = f2bf(okp[((size_t)(b*NS + s)) * NH + h]);
  }
  for (int ii = 0; ii < 32; ++ii){
    int lin = ii*256 + tid;
    int tt = lin >> 9, h = lin & 511;
    hdl[tt][h] = hd[((size_t)(b*NT + t0 + tt)) * NH + h];
  }
  vl[tid] = vat[tid]; vl[256 + tid] = vat[256 + tid];
  __syncthreads();
  #pragma unroll
  for (int pp = 0; pp < 2; ++pp){
    int p = pp*256 + tid;
    int tt = p >> 5, s = p & 31;
    float a = 0.f;
    #pragma unroll 4
    for (int h = 0; h < NH; ++h)
      a += vl[h] * ftanh(bf2f(hdl[tt][h]) + bf2f(okl[s][h]));
    attl[tt][s] = a;
  }
  __syncthreads();
  if (tid < 16){
    int tt = tid;
    float m = -1e30f;
    for (int s = 0; s < NS; ++s) m = fmaxf(m, attl[tt][s]);
    float sm = 0.f;
    for (int s = 0; s < NS; ++s) sm += fexp(attl[tt][s] - m);
    float lse = m + flog(sm);
    int g = b*NT + t0 + tt;
    float c = pmask[g] ? (attl[tt][ptg[g]] - lse) : 0.f;
    #pragma unroll
    for (int o = 1; o < 16; o <<= 1) c += __shfl_xor(c, o);
    if (tid == 0) atomicAdd(out + b, c);
  }
}

// ------------------------------- launch ---------------------------------------
extern "C" void kernel_launch(void* const* d_in, const int* in_sizes, int n_in,
                              void* d_out, int out_size, void* d_ws, size_t ws_size,
                              hipStream_t stream)
{
  (void)in_sizes; (void)n_in; (void)out_size; (void)ws_size;
  const float* embedding  = (const float*)d_in[0];
  const float* scope_enc  = (const float*)d_in[1];
  const float* spec_enc   = (const float*)d_in[2];
  const float* W_init     = (const float*)d_in[3];
  const float* b_init     = (const float*)d_in[4];
  const float* W_ih       = (const float*)d_in[5];
  const float* W_hh       = (const float*)d_in[6];
  const float* b_ih       = (const float*)d_in[7];
  const float* b_hh       = (const float*)d_in[8];
  const float* W_out      = (const float*)d_in[9];
  const float* b_out      = (const float*)d_in[10];
  const float* Wd         = (const float*)d_in[11];
  const float* We         = (const float*)d_in[12];
  const float* v_attn     = (const float*)d_in[13];
  const int* tokens_in    = (const int*)d_in[14];
  const int* tokens_out   = (const int*)d_in[15];
  const int* pointer_ids  = (const int*)d_in[16];
  const int* ptr_targets  = (const int*)d_in[17];
  const int* pointer_mask = (const int*)d_in[18];
  float* outF = (float*)d_out;

  uint8_t* wp = (uint8_t*)d_ws;
  auto carve = [&](size_t bytes)->void*{
    void* p = (void*)wp; wp += (bytes + 255) & ~(size_t)255; return p;
  };
  unsigned short* xp_bf    = (unsigned short*)carve((size_t)BT*1536*2);
  unsigned short* o_bf     = (unsigned short*)carve((size_t)BT*NH*2);
  float*          logitsF  = (float*)carve((size_t)BT*NV*4);
  unsigned short* hd_bf    = (unsigned short*)carve((size_t)BT*NH*2);
  float*          okp      = (float*)carve((size_t)NB*NS*NH*4);
  unsigned short* emb_bf   = (unsigned short*)carve((size_t)NV*NH*2);
  unsigned short* scope_bf = (unsigned short*)carve((size_t)NB*NS*NH*2);
  unsigned short* Wih_bf   = (unsigned short*)carve((size_t)3*NH*2*NH*2);
  unsigned short* Wout_bf  = (unsigned short*)carve((size_t)NV*NH*2);
  unsigned short* Wd_bf    = (unsigned short*)carve((size_t)NH*NH*2);
  unsigned short* We_bf    = (unsigned short*)carve((size_t)NH*NH*2);
  float*          h032     = (float*)carve((size_t)NB*NH*4);
  u64*            hx       = (u64*)carve((size_t)2*NB*256*8);
  u64*            hxL      = (u64*)carve((size_t)2*NB*256*8);
  unsigned short* zbuf     = (unsigned short*)carve(4096);

  hipLaunchKernelGGL(k_prep, dim3(1024), dim3(256), 0, stream,
                     embedding, scope_enc, W_ih, W_out, Wd, We,
                     emb_bf, scope_bf, Wih_bf, Wout_bf, Wd_bf, We_bf,
                     hx, hxL, outF, zbuf);
  hipLaunchKernelGGL(k_h0, dim3(NB), dim3(256), 0, stream, spec_enc, W_init, b_init,
                     h032, hx, hxL);
  GatherArgs ga{tokens_in, pointer_ids, pointer_mask, emb_bf, scope_bf, zbuf};
  GatherArgs g0{nullptr,nullptr,nullptr,nullptr,nullptr,nullptr};
  // x_proj = [emb|obj] @ W_ih^T + b_ih  -> bf16
  hipLaunchKernelGGL((k_gemm<1>), dim3(64,12), dim3(256), 0, stream,
                     (const unsigned short*)nullptr, Wih_bf, (float*)nullptr, xp_bf,
                     b_ih, BT, 1536, 1024, ga);
  // GRU scan (persistent, 256 blocks x 512 threads)
  hipLaunchKernelGGL(k_gru, dim3(256), dim3(512), 0, stream,
                     W_hh, b_hh, xp_bf, h032, hx, hxL, o_bf);
  // logits = o @ W_out^T + b_out -> f32
  hipLaunchKernelGGL((k_gemm<0>), dim3(64,1), dim3(256), 0, stream,
                     o_bf, Wout_bf, logitsF, (unsigned short*)nullptr, b_out, BT, NV, NH, g0);
  // hd = o @ Wd^T -> bf16
  hipLaunchKernelGGL((k_gemm<0>), dim3(64,4), dim3(256), 0, stream,
                     o_bf, Wd_bf, (float*)nullptr, hd_bf, (const float*)nullptr, BT, NH, NH, g0);
  // ok = scope @ We^T -> f32
  hipLaunchKernelGGL((k_gemm<0>), dim3(8,4), dim3(256), 0, stream,
                     scope_bf, We_bf, okp, (unsigned short*)nullptr, (const float*)nullptr,
                     NB*NS, NH, NH, g0);
  hipLaunchKernelGGL(k_tokll, dim3(128), dim3(256), 0, stream, logitsF, tokens_out, outF);
  hipLaunchKernelGGL(k_ptr, dim3(512), dim3(256), 0, stream,
                     hd_bf, okp, v_attn, ptr_targets, pointer_mask, outF);
}